// Round 2
// baseline (146.194 us; speedup 1.0000x reference)
//
#include <hip/hip_runtime.h>
#include <math.h>

#ifndef M_PI
#define M_PI 3.14159265358979323846
#endif

#define L2E_F 1.4426950408889634f
#define LN2_F 0.69314718055994531f

typedef float v2f __attribute__((ext_vector_type(2)));

static __device__ __forceinline__ float fexp2(float x) {
  return __builtin_amdgcn_exp2f(x);
}
static __device__ __forceinline__ float flog2(float x) {
  return __builtin_amdgcn_logf(x);
}
static __device__ __forceinline__ float rlane(float x, int l) {
  return __builtin_bit_cast(float, __builtin_amdgcn_readlane(__builtin_bit_cast(int, x), l));
}
static __device__ __forceinline__ v2f vfma(v2f a, v2f b, v2f c) {
  return __builtin_elementwise_fma(a, b, c);
}

// Layout: lane l of every wave owns terms t = s*64 + l, s = 0..11 (768 total).
// Each wave processes 64 points; per point, u/v/K are wave-uniform (readlane),
// term constants are per-lane VGPRs -> inner loop has NO memory ops.

__launch_bounds__(256)
__global__ void main_kernel(const float* __restrict__ U, const float* __restrict__ V,
                            const float* __restrict__ eps, const float* __restrict__ Iarr,
                            const float* __restrict__ Warr,
                            const float* __restrict__ psb, const float* __restrict__ psn,
                            const float* __restrict__ pdd, const float* __restrict__ prr,
                            float* __restrict__ partials) {
  const int tid = threadIdx.x;
  const int lane = tid & 63;
  const int wid = tid >> 6;

  // ---------------- fp32 prologue: per-lane term constants ----------------
  const float sb = psb[0], sn = psn[0], dd = pdd[0], rv = prr[0];
  const float rho = tanhf(rv);
  const float sig_eff = sn * sqrtf(1.0f - rho);
  const float sn2 = sn * sn * (1.0f - rho);
  const float inv_sn2 = 1.0f / sn2;
  const float inv_2snsq = 0.5f / (sn * sn);
  const float inv_snsq = 2.0f * inv_2snsq;

  float wmax = -1e30f;
  for (int k = 0; k < 10; ++k) wmax = fmaxf(wmax, Warr[k]);
  float wsum = 0.0f;
  for (int k = 0; k < 10; ++k) wsum += expf(Warr[k] - wmax);
  const float lse_w = wmax + logf(wsum);

  const float LG_ln = -0.12078224f;               // ln(gamma(1.5))
  const float Cs_ln = -logf(sn) - 0.5f * logf(2.0f * (float)M_PI)
                      - logf(sig_eff) - 0.5f * logf((float)M_PI);
  const float ln128 = logf(128.0f);
  const float I0 = Iarr[0], I1 = Iarr[1], I2 = Iarr[2], I3 = Iarr[3];

  v2f c2[6], b2[6], d2[6];
  float qmax = -1e30f, dmax = -1e30f;
#pragma unroll
  for (int s = 0; s < 12; ++s) {
    const int t = s * 64 + lane;
    const int j = t >> 7;                          // interface index 0..5
    const float Ia = (j < 3) ? I0 : ((j < 5) ? I1 : I2);
    const float Ib = (j == 0) ? I1 : ((j == 1 || j == 3) ? I2 : I3);
    const float e = eps[t];
    const float ux = fmaf(e, 2.0f * dd * sb, -dd * sb);
    const float arg = ux * (0.70710678f / sb);     // erfinv(erf(arg)) == arg
    const float In = fmaf((erff(arg) + 1.0f) * 0.5f, (Ib - Ia), Ia);
    const float G = (Ib - Ia) * (0.39894228f / sb) * expf(-arg * arg);
    const float lw = Warr[4 + j] - lse_w;
    const float q = -logf(G) - G * G * inv_sn2 + lw - ln128;
    const float dterm = 2.0f * G * inv_sn2;
    c2[s >> 1][s & 1] = (In * inv_snsq) * L2E_F;
    b2[s >> 1][s & 1] = (q - In * In * inv_2snsq) * L2E_F;
    d2[s >> 1][s & 1] = dterm * L2E_F;
    qmax = fmaxf(qmax, q * L2E_F);
    dmax = fmaxf(dmax, dterm * L2E_F);
  }
  // wave-reduce the bound constants (uniform afterwards)
#pragma unroll
  for (int m = 1; m < 64; m <<= 1) {
    qmax = fmaxf(qmax, __shfl_xor(qmax, m, 64));
    dmax = fmaxf(dmax, __shfl_xor(dmax, m, 64));
  }

  // interior components: lane p<4 owns component p; others contribute 0
  float Rmax = -1e30f;
  float cI_l = 0.0f, bI_l = -1e30f;
#pragma unroll
  for (int p = 0; p < 4; ++p) {
    const float Ip = (p == 0) ? I0 : ((p == 1) ? I1 : ((p == 2) ? I2 : I3));
    const float lw = Warr[p] - lse_w;
    const float bI_ln = lw + 0.69314718f - LG_ln - 3.0f * logf(sig_eff)
                        - logf(sn) - 0.5f * logf(2.0f * (float)M_PI)
                        - Cs_ln - Ip * Ip * inv_2snsq;
    Rmax = fmaxf(Rmax, (bI_ln + Ip * Ip * inv_2snsq) * L2E_F);
    if (lane == p) { cI_l = (Ip * inv_snsq) * L2E_F; bI_l = bI_ln * L2E_F; }
  }
  const float Cs2 = Cs_ln * L2E_F;
  const float cB = inv_2snsq * L2E_F;
  const float cA = inv_sn2 * L2E_F;

  // ---------------- point loop: 64 points per wave ----------------
  const int gw = blockIdx.x * 4 + wid;
  const int base = gw * 64;
  const float uvec = U[base + lane];
  const float vvec = V[base + lane];

  float tsum = 0.0f;
#pragma unroll 2
  for (int p = 0; p < 64; ++p) {
    const float u = rlane(uvec, p);
    const float v = rlane(vvec, p);
    const float l2v = flog2(v);
    const float ucB = u * u * cB;
    const float K = ucB + fmaxf(fmaf(v, dmax, qmax), l2v + Rmax);
    const float A2 = l2v - fmaf(v * v, cA, ucB);
    const float mK = -K, m2K = -2.0f * K;
    const v2f u2 = {u, u}, v2 = {v, v}, mK2 = {mK, mK}, m2K2 = {m2K, m2K};
    v2f acc = {0.0f, 0.0f};
#pragma unroll
    for (int s = 0; s < 6; ++s) {
      const v2f P = vfma(u2, c2[s], b2[s]);
      const v2f T = vfma(v2, d2[s], mK2);
      const v2f E1 = P + T;
      const v2f E2 = (P - T) + m2K2;
      v2f X1, X2;
      X1.x = fexp2(E1.x); X1.y = fexp2(E1.y);
      X2.x = fexp2(E2.x); X2.y = fexp2(E2.y);
      acc += X1 - X2;                              // each diff >= 0 (2*sinh z)
    }
    float lv = acc.x + acc.y
             + fexp2(fmaf(u, cI_l, bI_l) + (l2v - K));  // interior peel
#pragma unroll
    for (int m = 1; m < 64; m <<= 1) lv += __shfl_xor(lv, m, 64);
    const float tot = fmaxf(lv, 1e-38f);
    tsum += Cs2 + A2 + K + flog2(tot);
  }

  __shared__ float wsums[4];
  if (lane == 0) wsums[wid] = tsum;
  __syncthreads();
  if (tid == 0) partials[blockIdx.x] = (wsums[0] + wsums[1]) + (wsums[2] + wsums[3]);
}

__global__ void reduce_kernel(const float* __restrict__ partials,
                              float* __restrict__ out, int nb, float scale) {
  __shared__ float red[256];
  const int tid = threadIdx.x;
  float s = 0.0f;
  for (int i = tid; i < nb; i += 256) s += partials[i];
  red[tid] = s;
  __syncthreads();
  for (int k = 128; k > 0; k >>= 1) {
    if (tid < k) red[tid] += red[tid + k];
    __syncthreads();
  }
  if (tid == 0) out[0] = red[0] * scale;
}

extern "C" void kernel_launch(void* const* d_in, const int* in_sizes, int n_in,
                              void* d_out, int out_size, void* d_ws, size_t ws_size,
                              hipStream_t stream) {
  const float* u   = (const float*)d_in[0];
  const float* v   = (const float*)d_in[1];
  const float* eps = (const float*)d_in[2];
  const float* I   = (const float*)d_in[3];
  const float* W   = (const float*)d_in[4];
  const float* sb  = (const float*)d_in[5];
  const float* sn  = (const float*)d_in[6];
  const float* dd  = (const float*)d_in[7];
  const float* rr  = (const float*)d_in[8];
  const int M = in_sizes[0];
  float* partials = (float*)d_ws;
  const int nb = M / 256;   // 1024 blocks; 4 waves/block x 64 points/wave

  main_kernel<<<nb, 256, 0, stream>>>(u, v, eps, I, W, sb, sn, dd, rr, partials);
  reduce_kernel<<<1, 256, 0, stream>>>(partials, (float*)d_out, nb,
                                       -LN2_F / (float)M);
}

// Round 3
// 121.368 us; speedup vs baseline: 1.2046x; 1.2046x over previous
//
#include <hip/hip_runtime.h>
#include <math.h>

#ifndef M_PI
#define M_PI 3.14159265358979323846
#endif

#define L2E_F 1.4426950408889634f
#define LN2_F 0.69314718055994531f

typedef float v2f __attribute__((ext_vector_type(2)));

static __device__ __forceinline__ float fexp2(float x) {
  return __builtin_amdgcn_exp2f(x);
}
static __device__ __forceinline__ float flog2(float x) {
  return __builtin_amdgcn_logf(x);
}
static __device__ __forceinline__ v2f vfma(v2f a, v2f b, v2f c) {
  return __builtin_elementwise_fma(a, b, c);
}

// Block = 256 threads = 128 points x 2 halves.
// Thread (h,p): h = tid>>7 handles terms [h*384, h*384+384) for point p.
// Table is built per-block in an fp32 prologue (validated exact in R2),
// stored packed for v_pk_* math: Atab[k] = {c(2k), c(2k+1), b(2k), b(2k+1)},
// Dtab[q] = {d(4q), d(4q+1), d(4q+2), d(4q+3)}.  All loop reads are
// wave-broadcast (uniform address) -> zero bank conflicts.

__launch_bounds__(256, 8)
__global__ void main_kernel(const float* __restrict__ U, const float* __restrict__ V,
                            const float* __restrict__ eps, const float* __restrict__ Iarr,
                            const float* __restrict__ Warr,
                            const float* __restrict__ psb, const float* __restrict__ psn,
                            const float* __restrict__ pdd, const float* __restrict__ prr,
                            float* __restrict__ out, float scale) {
  __shared__ float4 Atab[384];
  __shared__ float4 Dtab[192];
  __shared__ float redq[256];
  __shared__ float redd[256];
  __shared__ float sums[128];
  __shared__ float red[256];

  const int tid = threadIdx.x;

  // ---------------- fp32 prologue ----------------
  const float sb = psb[0], sn = psn[0], dd = pdd[0], rv = prr[0];
  const float rho = tanhf(rv);
  const float sig_eff = sn * sqrtf(1.0f - rho);
  const float sn2 = sn * sn * (1.0f - rho);
  const float inv_sn2 = 1.0f / sn2;
  const float inv_2snsq = 0.5f / (sn * sn);
  const float inv_snsq = 2.0f * inv_2snsq;

  float wmax = -1e30f;
  for (int k = 0; k < 10; ++k) wmax = fmaxf(wmax, Warr[k]);
  float wsum = 0.0f;
  for (int k = 0; k < 10; ++k) wsum += expf(Warr[k] - wmax);
  const float lse_w = wmax + logf(wsum);

  const float LG_ln = -0.12078224f;  // ln(gamma(1.5))
  const float Cs_ln = -logf(sn) - 0.5f * logf(2.0f * (float)M_PI)
                      - logf(sig_eff) - 0.5f * logf((float)M_PI);
  const float ln128 = logf(128.0f);
  const float I0 = Iarr[0], I1 = Iarr[1], I2 = Iarr[2], I3 = Iarr[3];

  float qmax = -1e30f, dmax = -1e30f;
  for (int e = tid; e < 768; e += 256) {
    const int j = e >> 7;
    const float Ia = (j < 3) ? I0 : ((j < 5) ? I1 : I2);
    const float Ib = (j == 0) ? I1 : ((j == 1 || j == 3) ? I2 : I3);
    const float ee = eps[e];
    const float ux = fmaf(ee, 2.0f * dd * sb, -dd * sb);
    const float arg = ux * (0.70710678f / sb);   // erfinv(erf(arg)) == arg
    const float In = fmaf((erff(arg) + 1.0f) * 0.5f, (Ib - Ia), Ia);
    const float G = (Ib - Ia) * (0.39894228f / sb) * expf(-arg * arg);
    const float lw = Warr[4 + j] - lse_w;
    const float q = -logf(G) - G * G * inv_sn2 + lw - ln128;
    const float dt = 2.0f * G * inv_sn2;
    const float c2 = (In * inv_snsq) * L2E_F;
    const float b2 = (q - In * In * inv_2snsq) * L2E_F;
    const float d2 = dt * L2E_F;
    float* Af = (float*)&Atab[e >> 1];
    Af[e & 1] = c2;
    Af[2 + (e & 1)] = b2;
    ((float*)&Dtab[e >> 2])[e & 3] = d2;
    qmax = fmaxf(qmax, q * L2E_F);
    dmax = fmaxf(dmax, d2);
  }
  redq[tid] = qmax;
  redd[tid] = dmax;
  __syncthreads();
  for (int s = 128; s > 0; s >>= 1) {
    if (tid < s) {
      redq[tid] = fmaxf(redq[tid], redq[tid + s]);
      redd[tid] = fmaxf(redd[tid], redd[tid + s]);
    }
    __syncthreads();
  }
  qmax = redq[0];
  dmax = redd[0];

  float Rmax = -1e30f;
  float cI[4], bI[4];
#pragma unroll
  for (int p4 = 0; p4 < 4; ++p4) {
    const float Ip = (p4 == 0) ? I0 : ((p4 == 1) ? I1 : ((p4 == 2) ? I2 : I3));
    const float lw = Warr[p4] - lse_w;
    const float bI_ln = lw + 0.69314718f - LG_ln - 3.0f * logf(sig_eff)
                        - logf(sn) - 0.5f * logf(2.0f * (float)M_PI)
                        - Cs_ln - Ip * Ip * inv_2snsq;
    Rmax = fmaxf(Rmax, (bI_ln + Ip * Ip * inv_2snsq) * L2E_F);
    cI[p4] = (Ip * inv_snsq) * L2E_F;
    bI[p4] = bI_ln * L2E_F;
  }
  const float Cs2 = Cs_ln * L2E_F;
  const float cB = inv_2snsq * L2E_F;
  const float cA = inv_sn2 * L2E_F;

  // ---------------- main loop ----------------
  const int h = tid >> 7;
  const int p = tid & 127;
  const int m = blockIdx.x * 128 + p;
  const float u = U[m];
  const float v = V[m];
  const float l2v = flog2(v);
  const float ucB = u * u * cB;
  const float K = ucB + fmaxf(fmaf(v, dmax, qmax), l2v + Rmax);
  const float A2 = l2v - fmaf(v * v, cA, ucB);
  const v2f u2 = {u, u}, vv2 = {v, v}, mv2 = {-v, -v}, mK2 = {-K, -K};

  const float4* Ah = Atab + h * 192;
  const float4* Dh = Dtab + h * 96;
  v2f acc0 = {0.0f, 0.0f}, acc1 = {0.0f, 0.0f};
#pragma unroll 2
  for (int i = 0; i < 96; ++i) {
    const float4 a0 = Ah[2 * i];
    const float4 a1 = Ah[2 * i + 1];
    const float4 dp = Dh[i];
    v2f c0, b0, c1, b1, d0, d1;
    c0.x = a0.x; c0.y = a0.y; b0.x = a0.z; b0.y = a0.w;
    c1.x = a1.x; c1.y = a1.y; b1.x = a1.z; b1.y = a1.w;
    d0.x = dp.x; d0.y = dp.y; d1.x = dp.z; d1.y = dp.w;
    const v2f P0 = vfma(u2, c0, b0) + mK2;
    const v2f P1 = vfma(u2, c1, b1) + mK2;
    const v2f E1a = vfma(vv2, d0, P0);
    const v2f E2a = vfma(mv2, d0, P0);
    const v2f E1b = vfma(vv2, d1, P1);
    const v2f E2b = vfma(mv2, d1, P1);
    v2f X1a, X2a, X1b, X2b;
    X1a.x = fexp2(E1a.x); X1a.y = fexp2(E1a.y);
    X2a.x = fexp2(E2a.x); X2a.y = fexp2(E2a.y);
    X1b.x = fexp2(E1b.x); X1b.y = fexp2(E1b.y);
    X2b.x = fexp2(E2b.x); X2b.y = fexp2(E2b.y);
    acc0 += X1a - X2a;   // each diff >= 0 (2*sinh z)
    acc1 += X1b - X2b;
  }
  float myacc = (acc0.x + acc0.y) + (acc1.x + acc1.y);

  if (h == 1) sums[p] = myacc;
  __syncthreads();
  float lp2 = 0.0f;
  if (h == 0) {
    float accI = 0.0f;
#pragma unroll
    for (int p4 = 0; p4 < 4; ++p4)
      accI += fexp2(fmaf(u, cI[p4], bI[p4]) + (l2v - K));
    float tot = myacc + sums[p] + accI;
    tot = fmaxf(tot, 1e-38f);
    lp2 = Cs2 + A2 + K + flog2(tot);
  }
  red[tid] = lp2;
  __syncthreads();
  for (int s = 128; s > 0; s >>= 1) {
    if (tid < s) red[tid] += red[tid + s];
    __syncthreads();
  }
  if (tid == 0) atomicAdd(out, red[0] * scale);
}

extern "C" void kernel_launch(void* const* d_in, const int* in_sizes, int n_in,
                              void* d_out, int out_size, void* d_ws, size_t ws_size,
                              hipStream_t stream) {
  const float* u   = (const float*)d_in[0];
  const float* v   = (const float*)d_in[1];
  const float* eps = (const float*)d_in[2];
  const float* I   = (const float*)d_in[3];
  const float* W   = (const float*)d_in[4];
  const float* sb  = (const float*)d_in[5];
  const float* sn  = (const float*)d_in[6];
  const float* dd  = (const float*)d_in[7];
  const float* rr  = (const float*)d_in[8];
  const int M = in_sizes[0];
  const int nb = M / 128;  // 2048 blocks; 128 points/block, 2 threads/point

  hipMemsetAsync(d_out, 0, sizeof(float), stream);
  main_kernel<<<nb, 256, 0, stream>>>(u, v, eps, I, W, sb, sn, dd, rr,
                                      (float*)d_out, -LN2_F / (float)M);
}